// Round 4
// baseline (385.492 us; speedup 1.0000x reference)
//
#include <hip/hip_runtime.h>
#include <hip/hip_bf16.h>
#include <stdint.h>

typedef float f32x4 __attribute__((ext_vector_type(4)));
typedef _Float16 half8 __attribute__((ext_vector_type(8)));
typedef _Float16 half2_ __attribute__((ext_vector_type(2)));

#define B_ 4096
#define T_ 256
#define D_ 18
#define H_ 32
#define GK 8192   // T_*H_
#define GN 512

// ---------- helpers ----------
__device__ __forceinline__ float fsig(float x) {
  float e = __builtin_amdgcn_exp2f(-1.442695041f * x);
  return __builtin_amdgcn_rcpf(1.0f + e);
}
__device__ __forceinline__ float ftanh(float x) {
  float e = __builtin_amdgcn_exp2f(-2.885390082f * x);
  return 2.0f * __builtin_amdgcn_rcpf(1.0f + e) - 1.0f;
}
__device__ __forceinline__ half2_ pk16(float a, float b) {
  return __builtin_bit_cast(half2_, __builtin_amdgcn_cvt_pkrtz(a, b));
}

// ---------- kernel 1: W1 fp32 -> fp16 (RNE) ----------
__global__ __launch_bounds__(256) void cvtw1_kernel(const float* __restrict__ w1,
                                                    unsigned short* __restrict__ dst) {
  int i = blockIdx.x * 256 + threadIdx.x;  // float4 index, total 1048576
  float4 v = ((const float4*)w1)[i];
  unsigned short a = __builtin_bit_cast(unsigned short, (_Float16)v.x);
  unsigned short b = __builtin_bit_cast(unsigned short, (_Float16)v.y);
  unsigned short c = __builtin_bit_cast(unsigned short, (_Float16)v.z);
  unsigned short d = __builtin_bit_cast(unsigned short, (_Float16)v.w);
  uint2 o; o.x = (unsigned)a | ((unsigned)b << 16); o.y = (unsigned)c | ((unsigned)d << 16);
  ((uint2*)dst)[i] = o;
}

// ---------- kernel 2: MFMA LSTM (fp16, reg-prefetched x, swizzled h LDS) ----------
// Block = 512 thr (8 waves) owns 16 batch elements. Wave w owns M-tile w:
// tile-row m = hl*4 + gate, h_row = w*4 + hl, gate order (i,f,g,o);
// original W row = gate*32 + h_row. C layout row=lq*4+reg, col=lr =>
// lane (lq,lr) holds 4 gates of h_row = w*4+lq for element lr; c private.
// h exchanged via double-buffered LDS (fp16, XOR-swizzled rows of 64B).
// x B-fragments loaded per-lane from global, one 4-timestep chunk ahead.
__global__ __launch_bounds__(512) void lstm_kernel(
    const float* __restrict__ batch, const float* __restrict__ W_ih,
    const float* __restrict__ W_hh, const float* __restrict__ b_ih,
    const float* __restrict__ b_hh, _Float16* __restrict__ hs) {
  __shared__ _Float16 hb[2 * 512];  // [buf][el(16) x k(32)], chunk-swizzled

  const int tid = (int)threadIdx.x;
  const int lane = tid & 63;
  const int w = tid >> 6;
  const int lq = lane >> 4;
  const int lr = lane & 15;
  const int b0 = (int)blockIdx.x * 16;

  // constant A-fragments
  half8 wx, wh;
  {
    int grow = (lr & 3) * 32 + w * 4 + (lr >> 2);
#pragma unroll
    for (int j = 0; j < 8; ++j) {
      int k = lq * 8 + j;
      wx[j] = (k < D_) ? (_Float16)W_ih[grow * D_ + k] : (_Float16)0.0f;
      wh[j] = (_Float16)W_hh[grow * H_ + k];
    }
  }
  f32x4 bias4;
#pragma unroll
  for (int r = 0; r < 4; ++r) {
    int g = r * 32 + w * 4 + lq;
    bias4[r] = b_ih[g] + b_hh[g];
  }

  // zero h buffers (h(0)=0)
  for (int i = tid; i < 1024; i += 512) hb[i] = (_Float16)0.0f;

  // swizzled LDS offsets: row lr (64B), chunk c XOR'd with (lr>>1)&3
  const int rdoff = lr * 32 + ((lq ^ ((lr >> 1) & 3)) << 3);
  const int kcol = w * 4 + lq;  // h_row this lane produces
  const int wroff = lr * 32 + ((((kcol >> 3) ^ ((lr >> 1) & 3))) << 3) + (kcol & 7);
  _Float16* hsp = hs + (size_t)(b0 + lr) * GK + kcol;

  // x prefetch: lane (lq,lr) needs x[b0+lr][t][lq*8 .. lq*8+7] (d<18)
  float4 nxt[4][2];
#pragma unroll
  for (int tt = 0; tt < 4; ++tt) {
    nxt[tt][0] = make_float4(0.f, 0.f, 0.f, 0.f);
    nxt[tt][1] = make_float4(0.f, 0.f, 0.f, 0.f);
  }
  const float* xbase = batch + (size_t)(b0 + lr) * T_ * D_ + lq * 8;

#define LOAD_CHUNK(tb)                                                         \
  do {                                                                         \
    if (lq < 2) {                                                              \
      const float* p_ = xbase + (tb) * D_;                                     \
      _Pragma("unroll") for (int tt = 0; tt < 4; ++tt) {                       \
        nxt[tt][0] = *(const float4*)p_;                                       \
        nxt[tt][1] = *(const float4*)(p_ + 4);                                 \
        p_ += D_;                                                              \
      }                                                                        \
    } else if (lq == 2) {                                                      \
      const float* p_ = xbase + (tb) * D_;                                     \
      _Pragma("unroll") for (int tt = 0; tt < 4; ++tt) {                       \
        nxt[tt][0].x = p_[0]; nxt[tt][0].y = p_[1];                            \
        p_ += D_;                                                              \
      }                                                                        \
    }                                                                          \
  } while (0)

  LOAD_CHUNK(0);
  __syncthreads();

  float c = 0.0f;
  for (int tc = 0; tc < 64; ++tc) {
    // convert prefetched chunk to fp16 B-fragments
    half8 xf[4];
#pragma unroll
    for (int tt = 0; tt < 4; ++tt) {
      union { half8 h8; half2_ h2[4]; } u;
      u.h2[0] = pk16(nxt[tt][0].x, nxt[tt][0].y);
      u.h2[1] = pk16(nxt[tt][0].z, nxt[tt][0].w);
      u.h2[2] = pk16(nxt[tt][1].x, nxt[tt][1].y);
      u.h2[3] = pk16(nxt[tt][1].z, nxt[tt][1].w);
      xf[tt] = u.h8;
    }
    // prefetch next chunk (consumed 4 timesteps from now)
    LOAD_CHUNK(tc < 63 ? (tc + 1) * 4 : 252);

#pragma unroll
    for (int tt = 0; tt < 4; ++tt) {
      const int t = tc * 4 + tt;
      const int p = t & 1;
      half8 hf = *(const half8*)&hb[p * 512 + rdoff];
      f32x4 acc = bias4;
      acc = __builtin_amdgcn_mfma_f32_16x16x32_f16(wx, xf[tt], acc, 0, 0, 0);
      acc = __builtin_amdgcn_mfma_f32_16x16x32_f16(wh, hf, acc, 0, 0, 0);

      float iv = fsig(acc[0]);
      float fv = fsig(acc[1]);
      float gv = ftanh(acc[2]);
      float ov = fsig(acc[3]);
      c = fmaf(fv, c, iv * gv);
      float h = ov * ftanh(c);

      _Float16 hh = (_Float16)h;
      hsp[t * H_] = hh;                 // global hs[b][t][k]
      hb[(p ^ 1) * 512 + wroff] = hh;   // next-step h buffer
      __syncthreads();
    }
  }
#undef LOAD_CHUNK
}

// ---------- kernel 3: fp16 MFMA GEMM, BM=128 BN=64 BK=64, no split-K ----------
// A = hs [4096 x 8192], B = W1h [512 x 8192], C = hid [4096 x 512] fp32.
// 32 m-tiles x 8 n-tiles = 256 blocks (1/CU). 4 waves: 2x2, wave tile 64x32.
__global__ __launch_bounds__(256) void gemm_kernel(
    const _Float16* __restrict__ Ahs, const _Float16* __restrict__ Bw1,
    float* __restrict__ hid) {
  __shared__ _Float16 As[128 * 64];
  __shared__ _Float16 Bs[64 * 64];

  const int bid = (int)blockIdx.x;
  const int m0 = (bid & 31) << 7;
  const int n0 = (bid >> 5) << 6;

  const int tid = (int)threadIdx.x;
  const int lane = tid & 63, w = tid >> 6;
  const int wm = w & 1, wn = w >> 1;
  const int lq = lane >> 4, lr = lane & 15;

  // staging: LDS slot q of row holds global chunk q ^ (row&7)
  const _Float16* gA[4]; int lpA[4];
#pragma unroll
  for (int j = 0; j < 4; ++j) {
    int p = tid + 256 * j;               // 0..1023 : A chunks
    int row = p >> 3, q = p & 7, cg = q ^ (row & 7);
    gA[j] = Ahs + (size_t)(m0 + row) * GK + cg * 8;
    lpA[j] = p * 8;
  }
  const _Float16* gB[2]; int lpB[2];
#pragma unroll
  for (int j = 0; j < 2; ++j) {
    int p = tid + 256 * j;               // 0..511 : B chunks
    int row = p >> 3, q = p & 7, cg = q ^ (row & 7);
    gB[j] = Bw1 + (size_t)(n0 + row) * GK + cg * 8;
    lpB[j] = p * 8;
  }

  int offA[4][2], offB[2][2];
#pragma unroll
  for (int mt = 0; mt < 4; ++mt)
#pragma unroll
    for (int ks = 0; ks < 2; ++ks) {
      int m = wm * 64 + mt * 16 + lr;
      offA[mt][ks] = m * 64 + (((lq + ks * 4) ^ (m & 7)) << 3);
    }
#pragma unroll
  for (int nt = 0; nt < 2; ++nt)
#pragma unroll
    for (int ks = 0; ks < 2; ++ks) {
      int n = wn * 32 + nt * 16 + lr;
      offB[nt][ks] = n * 64 + (((lq + ks * 4) ^ (n & 7)) << 3);
    }

  f32x4 acc[4][2];
#pragma unroll
  for (int mt = 0; mt < 4; ++mt)
#pragma unroll
    for (int nt = 0; nt < 2; ++nt) {
      acc[mt][nt][0] = 0.f; acc[mt][nt][1] = 0.f;
      acc[mt][nt][2] = 0.f; acc[mt][nt][3] = 0.f;
    }

  for (int it = 0; it < 128; ++it) {
    half8 va[4], vb[2];
#pragma unroll
    for (int j = 0; j < 4; ++j) { va[j] = *(const half8*)gA[j]; gA[j] += 64; }
#pragma unroll
    for (int j = 0; j < 2; ++j) { vb[j] = *(const half8*)gB[j]; gB[j] += 64; }
    __syncthreads();
#pragma unroll
    for (int j = 0; j < 4; ++j) *(half8*)&As[lpA[j]] = va[j];
#pragma unroll
    for (int j = 0; j < 2; ++j) *(half8*)&Bs[lpB[j]] = vb[j];
    __syncthreads();

    half8 af[4][2], bf[2][2];
#pragma unroll
    for (int mt = 0; mt < 4; ++mt)
#pragma unroll
      for (int ks = 0; ks < 2; ++ks) af[mt][ks] = *(const half8*)&As[offA[mt][ks]];
#pragma unroll
    for (int nt = 0; nt < 2; ++nt)
#pragma unroll
      for (int ks = 0; ks < 2; ++ks) bf[nt][ks] = *(const half8*)&Bs[offB[nt][ks]];

#pragma unroll
    for (int ks = 0; ks < 2; ++ks)
#pragma unroll
      for (int mt = 0; mt < 4; ++mt)
#pragma unroll
        for (int nt = 0; nt < 2; ++nt)
          acc[mt][nt] = __builtin_amdgcn_mfma_f32_16x16x32_f16(af[mt][ks], bf[nt][ks], acc[mt][nt], 0, 0, 0);
  }

  // epilogue: C layout col=lr, row=lq*4+reg
#pragma unroll
  for (int mt = 0; mt < 4; ++mt)
#pragma unroll
    for (int nt = 0; nt < 2; ++nt) {
      int n = n0 + wn * 32 + nt * 16 + lr;
#pragma unroll
      for (int r = 0; r < 4; ++r) {
        int m = m0 + wm * 64 + mt * 16 + lq * 4 + r;
        hid[(size_t)m * GN + n] = acc[mt][nt][r];
      }
    }
}

// ---------- kernel 4: head ----------
__global__ __launch_bounds__(256) void head_kernel(const float* __restrict__ hid,
                                                   const float* __restrict__ b1,
                                                   const float* __restrict__ W2,
                                                   const float* __restrict__ b2,
                                                   float* __restrict__ out) {
  const int b = (int)(blockIdx.x * 4 + (threadIdx.x >> 6));
  const int l = (int)(threadIdx.x & 63);
  const float4* h4 = (const float4*)(hid + (size_t)b * GN);
  const float4* b14 = (const float4*)b1;
  const float4* w4 = (const float4*)W2;
  float s = 0.0f;
#pragma unroll
  for (int p = 0; p < 2; ++p) {
    int i = p * 64 + l;
    float4 hv = h4[i], bv = b14[i], wv = w4[i];
    float t0 = fmaxf(hv.x + bv.x, 0.0f);
    float t1 = fmaxf(hv.y + bv.y, 0.0f);
    float t2 = fmaxf(hv.z + bv.z, 0.0f);
    float t3 = fmaxf(hv.w + bv.w, 0.0f);
    s = fmaf(t0, wv.x, s); s = fmaf(t1, wv.y, s);
    s = fmaf(t2, wv.z, s); s = fmaf(t3, wv.w, s);
  }
#pragma unroll
  for (int off = 32; off >= 1; off >>= 1) s += __shfl_xor(s, off);
  if (l == 0) out[b] = s + b2[0];
}

extern "C" void kernel_launch(void* const* d_in, const int* in_sizes, int n_in,
                              void* d_out, int out_size, void* d_ws, size_t ws_size,
                              hipStream_t stream) {
  const float* batch = (const float*)d_in[0];
  const float* W_ih = (const float*)d_in[1];
  const float* W_hh = (const float*)d_in[2];
  const float* b_ih = (const float*)d_in[3];
  const float* b_hh = (const float*)d_in[4];
  const float* W1 = (const float*)d_in[5];
  const float* b1 = (const float*)d_in[6];
  const float* W2 = (const float*)d_in[7];
  const float* b2 = (const float*)d_in[8];
  float* out = (float*)d_out;

  char* ws = (char*)d_ws;
  _Float16* hs = (_Float16*)ws;                         // 4096*8192*2 = 67108864 B
  _Float16* w1h = (_Float16*)(ws + 67108864);           // 512*8192*2  =  8388608 B
  float* hid = (float*)(ws + 67108864 + 8388608);       // 4096*512*4  =  8388608 B

  cvtw1_kernel<<<4096, 256, 0, stream>>>(W1, (unsigned short*)w1h);
  lstm_kernel<<<256, 512, 0, stream>>>(batch, W_ih, W_hh, b_ih, b_hh, hs);
  gemm_kernel<<<256, 256, 0, stream>>>(hs, w1h, hid);
  head_kernel<<<1024, 256, 0, stream>>>(hid, b1, W2, b2, out);
}

// Round 5
// 330.935 us; speedup vs baseline: 1.1649x; 1.1649x over previous
//
#include <hip/hip_runtime.h>
#include <hip/hip_bf16.h>
#include <stdint.h>

typedef float f32x4 __attribute__((ext_vector_type(4)));
typedef _Float16 half8 __attribute__((ext_vector_type(8)));
typedef _Float16 half2_ __attribute__((ext_vector_type(2)));

#define B_ 4096
#define T_ 256
#define D_ 18
#define H_ 32
#define GK 8192   // T_*H_
#define GN 512
#define KSPLIT 4

// ---------- helpers ----------
__device__ __forceinline__ float fsig(float x) {
  float e = __builtin_amdgcn_exp2f(-1.442695041f * x);
  return __builtin_amdgcn_rcpf(1.0f + e);
}
__device__ __forceinline__ float ftanh(float x) {
  float e = __builtin_amdgcn_exp2f(-2.885390082f * x);
  return 2.0f * __builtin_amdgcn_rcpf(1.0f + e) - 1.0f;
}
__device__ __forceinline__ half2_ pk16(float a, float b) {
  return __builtin_bit_cast(half2_, __builtin_amdgcn_cvt_pkrtz(a, b));
}
// Barrier that drains ONLY LDS (lgkmcnt) — leaves global loads/stores in
// flight. Safe when all cross-wave communication is through LDS. This avoids
// __syncthreads()'s s_waitcnt vmcnt(0) drain (the R4 ~1700cy/t stall).
__device__ __forceinline__ void ldsbar() {
  asm volatile("s_waitcnt lgkmcnt(0)\n\ts_barrier" ::: "memory");
}

// ---------- kernel 1: W1 fp32 -> fp16 (RNE) ----------
__global__ __launch_bounds__(256) void cvtw1_kernel(const float* __restrict__ w1,
                                                    unsigned short* __restrict__ dst) {
  int i = blockIdx.x * 256 + threadIdx.x;  // float4 index, total 1048576
  float4 v = ((const float4*)w1)[i];
  unsigned short a = __builtin_bit_cast(unsigned short, (_Float16)v.x);
  unsigned short b = __builtin_bit_cast(unsigned short, (_Float16)v.y);
  unsigned short c = __builtin_bit_cast(unsigned short, (_Float16)v.z);
  unsigned short d = __builtin_bit_cast(unsigned short, (_Float16)v.w);
  uint2 o; o.x = (unsigned)a | ((unsigned)b << 16); o.y = (unsigned)c | ((unsigned)d << 16);
  ((uint2*)dst)[i] = o;
}

// ---------- kernel 2: MFMA LSTM (fp16, reg-prefetched x, LDS-only barrier) ----------
__global__ __launch_bounds__(512) void lstm_kernel(
    const float* __restrict__ batch, const float* __restrict__ W_ih,
    const float* __restrict__ W_hh, const float* __restrict__ b_ih,
    const float* __restrict__ b_hh, _Float16* __restrict__ hs) {
  __shared__ _Float16 hb[2 * 512];  // [buf][el(16) x k(32)], chunk-swizzled

  const int tid = (int)threadIdx.x;
  const int lane = tid & 63;
  const int w = tid >> 6;
  const int lq = lane >> 4;
  const int lr = lane & 15;
  const int b0 = (int)blockIdx.x * 16;

  // constant A-fragments (row m = hl*4+gate; original W row = gate*32 + w*4 + hl)
  half8 wx, wh;
  {
    int grow = (lr & 3) * 32 + w * 4 + (lr >> 2);
#pragma unroll
    for (int j = 0; j < 8; ++j) {
      int k = lq * 8 + j;
      wx[j] = (k < D_) ? (_Float16)W_ih[grow * D_ + k] : (_Float16)0.0f;
      wh[j] = (_Float16)W_hh[grow * H_ + k];
    }
  }
  f32x4 bias4;
#pragma unroll
  for (int r = 0; r < 4; ++r) {
    int g = r * 32 + w * 4 + lq;
    bias4[r] = b_ih[g] + b_hh[g];
  }

  // zero h buffers (h(0)=0)
  for (int i = tid; i < 1024; i += 512) hb[i] = (_Float16)0.0f;

  // swizzled LDS offsets: row lr (64B), chunk c XOR'd with (lr>>1)&3
  const int rdoff = lr * 32 + ((lq ^ ((lr >> 1) & 3)) << 3);
  const int kcol = w * 4 + lq;  // h_row this lane produces
  const int wroff = lr * 32 + ((((kcol >> 3) ^ ((lr >> 1) & 3))) << 3) + (kcol & 7);
  _Float16* hsp = hs + (size_t)(b0 + lr) * GK + kcol;

  // x prefetch: lane (lq,lr) needs x[b0+lr][t][lq*8 .. lq*8+7] (d<18)
  float4 nxt[4][2];
#pragma unroll
  for (int tt = 0; tt < 4; ++tt) {
    nxt[tt][0] = make_float4(0.f, 0.f, 0.f, 0.f);
    nxt[tt][1] = make_float4(0.f, 0.f, 0.f, 0.f);
  }
  const float* xbase = batch + (size_t)(b0 + lr) * T_ * D_ + lq * 8;

#define LOAD_CHUNK(tb)                                                         \
  do {                                                                         \
    if (lq < 2) {                                                              \
      const float* p_ = xbase + (tb) * D_;                                     \
      _Pragma("unroll") for (int tt = 0; tt < 4; ++tt) {                       \
        nxt[tt][0] = *(const float4*)p_;                                       \
        nxt[tt][1] = *(const float4*)(p_ + 4);                                 \
        p_ += D_;                                                              \
      }                                                                        \
    } else if (lq == 2) {                                                      \
      const float* p_ = xbase + (tb) * D_;                                     \
      _Pragma("unroll") for (int tt = 0; tt < 4; ++tt) {                       \
        nxt[tt][0].x = p_[0]; nxt[tt][0].y = p_[1];                            \
        p_ += D_;                                                              \
      }                                                                        \
    }                                                                          \
  } while (0)

  LOAD_CHUNK(0);
  ldsbar();

  float c = 0.0f;
  for (int tc = 0; tc < 64; ++tc) {
    // convert prefetched chunk to fp16 B-fragments
    half8 xf[4];
#pragma unroll
    for (int tt = 0; tt < 4; ++tt) {
      union { half8 h8; half2_ h2[4]; } u;
      u.h2[0] = pk16(nxt[tt][0].x, nxt[tt][0].y);
      u.h2[1] = pk16(nxt[tt][0].z, nxt[tt][0].w);
      u.h2[2] = pk16(nxt[tt][1].x, nxt[tt][1].y);
      u.h2[3] = pk16(nxt[tt][1].z, nxt[tt][1].w);
      xf[tt] = u.h8;
    }
    // prefetch next chunk (consumed 4 timesteps from now; stays in flight
    // across the ldsbar barriers below — no vmcnt drain)
    LOAD_CHUNK(tc < 63 ? (tc + 1) * 4 : 252);

#pragma unroll
    for (int tt = 0; tt < 4; ++tt) {
      const int t = tc * 4 + tt;
      const int p = t & 1;
      half8 hf = *(const half8*)&hb[p * 512 + rdoff];
      f32x4 acc = bias4;
      acc = __builtin_amdgcn_mfma_f32_16x16x32_f16(wx, xf[tt], acc, 0, 0, 0);
      acc = __builtin_amdgcn_mfma_f32_16x16x32_f16(wh, hf, acc, 0, 0, 0);

      float iv = fsig(acc[0]);
      float fv = fsig(acc[1]);
      float gv = ftanh(acc[2]);
      float ov = fsig(acc[3]);
      c = fmaf(fv, c, iv * gv);
      float h = ov * ftanh(c);

      _Float16 hh = (_Float16)h;
      hsp[t * H_] = hh;                 // global hs[b][t][k] (never drained in-loop)
      hb[(p ^ 1) * 512 + wroff] = hh;   // next-step h buffer
      ldsbar();
    }
  }
#undef LOAD_CHUNK
}

// ---------- kernel 3: fp16 MFMA GEMM, BM=BN=128 BK=64, split-K=4 ----------
// A = hs [4096 x 8192], B = W1h [512 x 8192], partials [KSPLIT][4096 x 512] fp32.
// 32 m x 4 n x 4 ksplit = 512 blocks (2/CU). Pipelined single-buffer K-loop
// with LDS-only barriers: next-iter global loads stay in flight across both
// barriers and are waited only at the ds_write that consumes them.
__global__ __launch_bounds__(256, 2) void gemm_kernel(
    const _Float16* __restrict__ Ahs, const _Float16* __restrict__ Bw1,
    float* __restrict__ part) {
  __shared__ _Float16 As[128 * 64];
  __shared__ _Float16 Bs[128 * 64];

  const int bid = (int)blockIdx.x;
  const int m0 = (bid & 31) << 7;
  const int n0 = ((bid >> 5) & 3) << 7;
  const int ksp = bid >> 7;
  const int k0 = ksp << 11;   // * 2048
  float* outp = part + (size_t)ksp * ((size_t)B_ * GN);

  const int tid = (int)threadIdx.x;
  const int lane = tid & 63, w = tid >> 6;
  const int wm = w & 1, wn = w >> 1;
  const int lq = lane >> 4, lr = lane & 15;

  // staging: LDS slot q of row holds global chunk q ^ (row&7)
  const _Float16* gA[4]; const _Float16* gB[4]; int lp[4];
#pragma unroll
  for (int j = 0; j < 4; ++j) {
    int p = tid + 256 * j;               // 0..1023
    int row = p >> 3, q = p & 7, cg = q ^ (row & 7);
    gA[j] = Ahs + (size_t)(m0 + row) * GK + k0 + cg * 8;
    gB[j] = Bw1 + (size_t)(n0 + row) * GK + k0 + cg * 8;
    lp[j] = p * 8;
  }

  int offA[4][2], offB[4][2];
#pragma unroll
  for (int mt = 0; mt < 4; ++mt)
#pragma unroll
    for (int ks = 0; ks < 2; ++ks) {
      int m = wm * 64 + mt * 16 + lr;
      offA[mt][ks] = m * 64 + (((lq + ks * 4) ^ (m & 7)) << 3);
      int n = wn * 64 + mt * 16 + lr;
      offB[mt][ks] = n * 64 + (((lq + ks * 4) ^ (n & 7)) << 3);
    }

  f32x4 acc[4][4];
#pragma unroll
  for (int mt = 0; mt < 4; ++mt)
#pragma unroll
    for (int nt = 0; nt < 4; ++nt) {
      acc[mt][nt][0] = 0.f; acc[mt][nt][1] = 0.f;
      acc[mt][nt][2] = 0.f; acc[mt][nt][3] = 0.f;
    }

  // prefetch iter 0
  half8 va[4], vb[4];
#pragma unroll
  for (int j = 0; j < 4; ++j) { va[j] = *(const half8*)gA[j]; vb[j] = *(const half8*)gB[j]; }

  for (int it = 0; it < 32; ++it) {
    ldsbar();   // all waves done reading LDS of previous iter
#pragma unroll
    for (int j = 0; j < 4; ++j) {
      *(half8*)&As[lp[j]] = va[j];       // vmcnt wait happens here (hidden by prior MFMAs)
      *(half8*)&Bs[lp[j]] = vb[j];
    }
    ldsbar();   // writes visible

    // issue next-iter loads immediately; they fly across the MFMAs + barriers
    if (it < 31) {
#pragma unroll
      for (int j = 0; j < 4; ++j) {
        gA[j] += 64; gB[j] += 64;
        va[j] = *(const half8*)gA[j];
        vb[j] = *(const half8*)gB[j];
      }
    }

    half8 af[4][2], bf[4][2];
#pragma unroll
    for (int mt = 0; mt < 4; ++mt)
#pragma unroll
      for (int ks = 0; ks < 2; ++ks) {
        af[mt][ks] = *(const half8*)&As[offA[mt][ks]];
        bf[mt][ks] = *(const half8*)&Bs[offB[mt][ks]];
      }
#pragma unroll
    for (int ks = 0; ks < 2; ++ks)
#pragma unroll
      for (int mt = 0; mt < 4; ++mt)
#pragma unroll
        for (int nt = 0; nt < 4; ++nt)
          acc[mt][nt] = __builtin_amdgcn_mfma_f32_16x16x32_f16(af[mt][ks], bf[nt][ks], acc[mt][nt], 0, 0, 0);
  }

  // epilogue: C layout col=lr, row=lq*4+reg; plain stores to this split's buffer
#pragma unroll
  for (int mt = 0; mt < 4; ++mt)
#pragma unroll
    for (int nt = 0; nt < 4; ++nt) {
      int n = n0 + wn * 64 + nt * 16 + lr;
#pragma unroll
      for (int r = 0; r < 4; ++r) {
        int m = m0 + wm * 64 + mt * 16 + lq * 4 + r;
        outp[(size_t)m * GN + n] = acc[mt][nt][r];
      }
    }
}

// ---------- kernel 4: head — sum KSPLIT partials, bias, relu, dot W2 ----------
__global__ __launch_bounds__(256) void head_kernel(const float* __restrict__ part,
                                                   const float* __restrict__ b1,
                                                   const float* __restrict__ W2,
                                                   const float* __restrict__ b2,
                                                   float* __restrict__ out) {
  const int b = (int)(blockIdx.x * 4 + (threadIdx.x >> 6));
  const int l = (int)(threadIdx.x & 63);
  const size_t stride = (size_t)B_ * GN;
  const float4* b14 = (const float4*)b1;
  const float4* w4 = (const float4*)W2;
  float s = 0.0f;
#pragma unroll
  for (int p = 0; p < 2; ++p) {
    int i = p * 64 + l;
    float4 hv = ((const float4*)(part + (size_t)b * GN))[i];
#pragma unroll
    for (int sp = 1; sp < KSPLIT; ++sp) {
      float4 pv = ((const float4*)(part + sp * stride + (size_t)b * GN))[i];
      hv.x += pv.x; hv.y += pv.y; hv.z += pv.z; hv.w += pv.w;
    }
    float4 bv = b14[i], wv = w4[i];
    float t0 = fmaxf(hv.x + bv.x, 0.0f);
    float t1 = fmaxf(hv.y + bv.y, 0.0f);
    float t2 = fmaxf(hv.z + bv.z, 0.0f);
    float t3 = fmaxf(hv.w + bv.w, 0.0f);
    s = fmaf(t0, wv.x, s); s = fmaf(t1, wv.y, s);
    s = fmaf(t2, wv.z, s); s = fmaf(t3, wv.w, s);
  }
#pragma unroll
  for (int off = 32; off >= 1; off >>= 1) s += __shfl_xor(s, off);
  if (l == 0) out[b] = s + b2[0];
}

extern "C" void kernel_launch(void* const* d_in, const int* in_sizes, int n_in,
                              void* d_out, int out_size, void* d_ws, size_t ws_size,
                              hipStream_t stream) {
  const float* batch = (const float*)d_in[0];
  const float* W_ih = (const float*)d_in[1];
  const float* W_hh = (const float*)d_in[2];
  const float* b_ih = (const float*)d_in[3];
  const float* b_hh = (const float*)d_in[4];
  const float* W1 = (const float*)d_in[5];
  const float* b1 = (const float*)d_in[6];
  const float* W2 = (const float*)d_in[7];
  const float* b2 = (const float*)d_in[8];
  float* out = (float*)d_out;

  char* ws = (char*)d_ws;
  _Float16* hs = (_Float16*)ws;                         // 4096*8192*2 = 67108864 B
  _Float16* w1h = (_Float16*)(ws + 67108864);           // 512*8192*2  =  8388608 B
  float* part = (float*)(ws + 67108864 + 8388608);      // 4*4096*512*4 = 33554432 B

  cvtw1_kernel<<<4096, 256, 0, stream>>>(W1, (unsigned short*)w1h);
  lstm_kernel<<<256, 512, 0, stream>>>(batch, W_ih, W_hh, b_ih, b_hh, hs);
  gemm_kernel<<<512, 256, 0, stream>>>(hs, w1h, part);
  head_kernel<<<1024, 256, 0, stream>>>(part, b1, W2, b2, out);
}